// Round 3
// baseline (377.278 us; speedup 1.0000x reference)
//
#include <hip/hip_runtime.h>
#include <math.h>

#define NA 16
#define NBEAM 12
#define NUSER 8

// ws layout: [0 .. 1535]  : steering table, 12 beams x (16 cos | 16 sin) floats
//            [1536..1543] : double accumulator
#define ACC_OFFSET 1536

__global__ void mtl_angles_kernel(const float* __restrict__ Hc_r, const float* __restrict__ Hc_i,
                                  const float* __restrict__ Hs_r, const float* __restrict__ Hs_i,
                                  float* __restrict__ table, double* __restrict__ acc) {
    int t = threadIdx.x;
    if (t == 0) *acc = 0.0;          // zero the reduction accumulator (ws is poisoned 0xAA)
    if (t >= NBEAM) return;

    const float* re;
    const float* im;
    if (t < NUSER) { re = Hc_r + t * NA;           im = Hc_i + t * NA; }          // Hc[0, t, :]
    else           { re = Hs_r + (t - NUSER) * NA; im = Hs_i + (t - NUSER) * NA; } // Hs[0, t, :]

    const float PI_F   = 3.14159265358979323846f;
    const float TWO_PI = 6.28318530717958647692f;

    float ph[NA];
    #pragma unroll
    for (int n = 0; n < NA; ++n) ph[n] = atan2f(im[n], re[n]);

    // unwrapped[0]=0; unwrapped[n]=cumsum of wrapped diffs. n_c = n - 7.5, sum(n_c^2)=340.
    float unw = 0.f, dotsum = 0.f;
    #pragma unroll
    for (int n = 1; n < NA; ++n) {
        float pd = ph[n] - ph[n - 1];
        float x  = pd + PI_F;
        float m  = fmodf(x, TWO_PI);       // python % has sign of divisor
        if (m < 0.f) m += TWO_PI;
        pd = m - PI_F;
        unw += pd;
        dotsum += unw * ((float)n - 7.5f);
    }
    float slope = dotsum / 340.0f;
    float sin_theta = slope / PI_F;        // slope * WAVELENGTH / (2*pi*D), D=0.5, lambda=1
    sin_theta = fminf(1.0f, fmaxf(-1.0f, sin_theta));
    // angle = -asin(sin_theta); steering uses sin(angle) = -sin_theta
    float st = -sin_theta;

    #pragma unroll
    for (int n = 0; n < NA; ++n) {
        float phase = PI_F * st * (float)n;    // 2*pi*D*st*n/lambda = pi*st*n
        table[t * 2 * NA + n]      = cosf(phase);
        table[t * 2 * NA + NA + n] = sinf(phase);
    }
}

__device__ __forceinline__ float dot4(float4 a, float4 b) {
    return a.x * b.x + a.y * b.y + a.z * b.z + a.w * b.w;
}

// Async global->LDS, 16 B per lane. LDS dest is wave-uniform base + lane*16.
__device__ __forceinline__ void load_lds16(const float* g, float* l) {
    __builtin_amdgcn_global_load_lds(
        (const __attribute__((address_space(1))) void*)g,
        (__attribute__((address_space(3))) void*)l, 16, 0, 0);
}

// One beam's gain: |(Wr+iWi) . (c - i s)| given the beam's 32-float table row.
__device__ __forceinline__ float beam_gain(const float4* w, const float* trow) {
    const float4* tc = (const float4*)trow;
    float re = 0.f, im = 0.f;
    #pragma unroll
    for (int q = 0; q < 4; ++q) {
        float4 c = tc[q], s = tc[q + 4];
        float4 wr = w[q], wi = w[q + 4];
        re += dot4(wr, c) + dot4(wi, s);
        im += dot4(wi, c) - dot4(wr, s);
    }
    return sqrtf(re * re + im * im);
}

// Full-row loss (all 12 beams) — used only by the generic tail path.
__device__ __forceinline__ float row_loss(const float4* w, const float* tbs) {
    float minU = 3.4e38f, sumU = 0.f, sumT = 0.f;
    #pragma unroll 1
    for (int j = 0; j < NBEAM; ++j) {
        float g = beam_gain(w, tbs + j * 32);
        if (j < NUSER) { minU = fminf(minU, g); sumU += g; }
        else           { sumT += g; }
    }
    return -2.0f * (minU + 0.1f * sumU) - 0.05f * sumT;
}

// R8: prefetch depth 1 -> 2. R7's compute body, swizzle, pair-split unchanged.
//  - R5/R7 showed the kernel is TLP-invariant (8 vs 16 waves/CU: same time) at
//    ~4.5 TB/s demand vs 6.3 achievable. Remaining theory: depth-1 prefetch
//    exposes burst latency - each tile's stage has only ~1 compute-phase of
//    budget before its vmcnt wait; under full-stream congestion load latency
//    exceeds that, and the stall is synchronized per-wave (so extra waves
//    don't hide it -> explains TLP-invariance).
//  - Triple buffer per wave (A=compute, B=ready, C=staging), steady-state
//    s_waitcnt vmcnt(8): wait for the oldest tile's 4 loads, keep 2 tiles
//    (8 loads) in flight. Each stage now has ~2 compute-phases of budget.
//  - LDS: 4 waves x 3 x 4 KB + table ~= 50 KB -> 3 blocks/CU = 12 waves/CU
//    (safe per the TLP-invariance result). Grid 768 = exactly resident.
//    waves_per_eu(3,3) gives the allocator a ~170-VGPR budget (no R6 squeeze).
__global__ __launch_bounds__(256)
__attribute__((amdgpu_waves_per_eu(3, 3)))
void mtl_gains_kernel(const float* __restrict__ W,
                      const float* __restrict__ table,
                      double* __restrict__ acc, int rows) {
    __shared__ float sh[4 * 3 * 1024];      // 48 KB: 4 waves x 3 buffers x 4 KB
    __shared__ float tbs[NBEAM * 2 * NA];   // steering table, 384 floats
    __shared__ float wsum[4];

    const int t = threadIdx.x;
    for (int i = t; i < NBEAM * 2 * NA; i += blockDim.x) tbs[i] = table[i];
    __syncthreads();

    const int wid  = t >> 6;
    const int lane = t & 63;
    float* bA = sh + wid * 3072;
    float* bB = bA + 1024;
    float* bC = bB + 1024;

    // Source-side XOR swizzle (verified R5-R7): staging instr k, lane ->
    // LDS slot p = k*64+lane; row(p)=k*8+(lane>>3), q(p)=lane&7; source quad =
    // row*8 + ((lane&7) ^ (lane>>3)). LDS dest stays contiguous for
    // global_load_lds; row-major b128 reads hit all 32 banks.
    const int sq      = (lane & 7) ^ ((lane >> 3) & 7);
    const int src_off = (lane >> 3) * 32 + sq * 4;     // floats within the 1024-float tile

    const int ntiles = rows >> 5;                       // 32-row tiles (62500)
    const int nwaves = gridDim.x * 4;
    const int gw     = blockIdx.x * 4 + wid;
    const int cnt    = ntiles / nwaves;
    const int rem    = ntiles % nwaves;
    const int t0     = gw * cnt + (gw < rem ? gw : rem);
    const int t1     = t0 + cnt + (gw < rem ? 1 : 0);

    // Pair scheme: lanes l and l^32 both process row = lane&31 (same-address
    // LDS read = broadcast). Beam partition per half h = lane>>5:
    //   user beams   h*4 .. h*4+3, target beams 8+2h, 9+2h
    // -> identical uniform code on both halves, combine via 3 shfl_xor(32).
    const int h      = lane >> 5;
    const int row    = lane & 31;
    const float* tbU = tbs + h * 4 * 32;
    const float* tbT = tbs + (8 + h * 2) * 32;

    float local = 0.f;

    if (t0 < t1) {
        // prologue: stage t0 -> A, t0+1 -> B (if present). 4 loads per tile.
        {
            const float* src = W + (size_t)t0 * 1024 + src_off;
            #pragma unroll
            for (int k = 0; k < 4; ++k) load_lds16(src + k * 256, bA + k * 256);
        }
        if (t0 + 1 < t1) {
            const float* src = W + (size_t)(t0 + 1) * 1024 + src_off;
            #pragma unroll
            for (int k = 0; k < 4; ++k) load_lds16(src + k * 256, bB + k * 256);
        }
        #pragma unroll 1
        for (int tt = t0; tt < t1; ++tt) {
            if (tt + 2 < t1) {
                const float* src = W + (size_t)(tt + 2) * 1024 + src_off;
                #pragma unroll
                for (int k = 0; k < 4; ++k) load_lds16(src + k * 256, bC + k * 256);
                // outstanding: {tt, tt+1, tt+2} = 12 loads. Complete tile tt's
                // 4 (oldest); keep 2 tiles = 8 loads in flight during compute.
                asm volatile("s_waitcnt vmcnt(8)" ::: "memory");
            } else if (tt + 1 < t1) {
                // outstanding: {tt, tt+1} = 8; complete tt's 4.
                asm volatile("s_waitcnt vmcnt(4)" ::: "memory");
            } else {
                asm volatile("s_waitcnt vmcnt(0)" ::: "memory");
            }

            const float* myrow = bA + row * 32;        // lanes l, l^32: same addr (broadcast)
            float4 w[8];
            #pragma unroll
            for (int q = 0; q < 8; ++q) {
                int s = q ^ (row & 7);
                w[q] = *(const float4*)(myrow + s * 4);
            }

            float minU = 3.4e38f, sumU = 0.f, sumT = 0.f;
            #pragma unroll 1
            for (int jj = 0; jj < 4; ++jj) {
                float g = beam_gain(w, tbU + jj * 32);
                minU = fminf(minU, g);
                sumU += g;
            }
            #pragma unroll 1
            for (int jj = 0; jj < 2; ++jj) {
                sumT += beam_gain(w, tbT + jj * 32);
            }
            // combine the two half-beam partials across lane pairs (l <-> l^32)
            minU = fminf(minU, __shfl_xor(minU, 32));
            sumU += __shfl_xor(sumU, 32);
            sumT += __shfl_xor(sumT, 32);
            // both lanes of the pair accumulate the full row loss -> weight 0.5
            local += 0.5f * (-2.0f * (minU + 0.1f * sumU) - 0.05f * sumT);

            // rotate buffers: A<-B (next compute), B<-C (ready), C<-A (free)
            float* tmp = bA; bA = bB; bB = bC; bC = tmp;
        }
    }

    // generic tail (rows % 32) — zero iterations for rows = 2,000,000
    int tailbase = ntiles << 5;
    if (blockIdx.x == 0) {
        int r = tailbase + t;
        if (r < rows) {
            const float4* wp = (const float4*)(W + (size_t)r * 32);
            float4 w[8];
            #pragma unroll
            for (int i = 0; i < 8; ++i) w[i] = wp[i];
            local += row_loss(w, tbs);
        }
    }

    // wave reduce (64 lanes)
    #pragma unroll
    for (int off = 32; off > 0; off >>= 1) local += __shfl_down(local, off);
    if (lane == 0) wsum[wid] = local;
    __syncthreads();
    if (t == 0) {
        float b = wsum[0] + wsum[1] + wsum[2] + wsum[3];
        atomicAdd(acc, (double)b);
    }
}

__global__ void mtl_finalize_kernel(const double* __restrict__ acc, float* __restrict__ out, int rows) {
    if (threadIdx.x == 0) out[0] = (float)(*acc / (double)rows);
}

extern "C" void kernel_launch(void* const* d_in, const int* in_sizes, int n_in,
                              void* d_out, int out_size, void* d_ws, size_t ws_size,
                              hipStream_t stream) {
    const float* W    = (const float*)d_in[0];
    const float* Hc_r = (const float*)d_in[1];
    const float* Hc_i = (const float*)d_in[2];
    const float* Hs_r = (const float*)d_in[3];
    const float* Hs_i = (const float*)d_in[4];
    float* out = (float*)d_out;

    int rows = in_sizes[0] / (2 * NA);   // 2,000,000
    float*  table = (float*)d_ws;
    double* acc   = (double*)((char*)d_ws + ACC_OFFSET);

    mtl_angles_kernel<<<1, 64, 0, stream>>>(Hc_r, Hc_i, Hs_r, Hs_i, table, acc);

    // 768 blocks x 4 waves = 3072 waves; ~50 KB LDS/block -> 3 blocks/CU
    // resident = 12 waves/CU, prefetch depth 2 per wave.
    mtl_gains_kernel<<<768, 256, 0, stream>>>(W, table, acc, rows);

    mtl_finalize_kernel<<<1, 64, 0, stream>>>(acc, out, rows);
}